// Round 11
// baseline (306.267 us; speedup 1.0000x reference)
//
#include <hip/hip_runtime.h>
#include <hip/hip_bf16.h>

#define NV 23
#define NTOT 16384
#define FLAT (NV * 256)    // 5888 floats per slab
#define FLAT4 (FLAT / 4)   // 1472
#define CH 184             // f32x4 per wave (1472/8)
#define NS 3               // reg slots per chunk (64+64+56)
#define SLAB 23552         // slab bytes

// stats: X'[2]@0 (32768) | raw[2]@32768 (47104) -> 79872 B => 2 blocks/CU.
// grid 1024 x NB0=16.
#define NB0 16
#define ROFF0 32768
// write: X'[2]@0 | raw[3]@32768 (70656) | O@103424 (23552) -> 126976; grid 512 x NB1=32
#define NB1 32
#define ROFF1 32768
#define OOFF1 103424

typedef short s16x8 __attribute__((ext_vector_type(8)));
typedef float f32x4 __attribute__((ext_vector_type(4)));
typedef unsigned u32x4 __attribute__((ext_vector_type(4)));

// x/23 for 0 <= x < 61681
__device__ __forceinline__ int divNV(int x) { return (int)(((unsigned)x * 45591u) >> 20); }
// f32 -> bf16 bits, RNE
__device__ __forceinline__ unsigned f2bf(float f) {
  unsigned u = __float_as_uint(f);
  u += 0x7fffu + ((u >> 16) & 1u);
  return u >> 16;
}
// X' column swizzle (16-B granules): 6 distinct groups for w-strides of 4
// (form writes ~conflict-free), read rows pair-wise 2-way (free).
__device__ __forceinline__ int fsw(int w) { return ((w + (w >> 3)) * 3) & 7; }

// async global->LDS DMA, 16B per lane (lds dest wave-uniform, HW adds lane*16)
__device__ __forceinline__ void gl_lds16(const void* g, void* l) {
  __builtin_amdgcn_global_load_lds(
      (const __attribute__((address_space(1))) unsigned*)(unsigned long long)(uintptr_t)g,
      (__attribute__((address_space(3))) unsigned*)(unsigned)(uintptr_t)l, 16, 0, 0);
}

// ws layout (bytes): Wt@0 (131072) | tab@131072 (23552) | sum@154624 | ssq@178176
//                    | An2@201728 | Bn2@225280 -> 248832 total
__global__ void k_prep(const float* __restrict__ W, const float* __restrict__ mask,
                       short* __restrict__ Wt, unsigned* __restrict__ tab,
                       float* __restrict__ sums) {
  int idx = blockIdx.x * 256 + threadIdx.x;  // grid 256 -> 65536
  int d = idx >> 8, c = idx & 255;
  Wt[idx] = (short)f2bf(W[c * 256 + d]);     // W^T in bf16: Wt[d][c]
  if (idx < FLAT) {
    // p = idx = c*23 + v ; w = (v - c) mod 23 ; swizzled LDS byte offset
    int cc = divNV(idx);
    int v = idx - NV * cc;
    int cm = cc - NV * divNV(cc);
    int w = v - cm; w += (w >> 31) & NV;
    unsigned off = (unsigned)((w << 9) + ((cc << 1) ^ (fsw(w) << 4)));
    tab[idx] = (f2bf(tanhf(mask[(w << 8) + cc]) + 1.0f) << 16) | off;
  }
  if (idx < 2 * FLAT) sums[idx] = 0.0f;      // zero sum+ssq
}

__global__ void k_finalize(const float* __restrict__ sum, const float* __restrict__ ssq,
                           const float* __restrict__ bnw, const float* __restrict__ bnb,
                           float* __restrict__ An2, float* __restrict__ Bn2) {
  int idx = blockIdx.x * 256 + threadIdx.x;  // (w,d) feature in y-space
  if (idx >= FLAT) return;
  int w = idx >> 8, d = idx & 255;
  float mean = sum[idx] * (1.0f / NTOT);
  float var  = ssq[idx] * (1.0f / NTOT) - mean * mean;
  float inv  = rsqrtf(var + 1e-5f);
  int i = w + d; i -= NV * divNV(i);         // out-shift row i = (w+d) % 23
  float a = inv * bnw[i * 256 + d];
  An2[d * NV + i] = a;                       // j-indexed (flat out order)
  Bn2[d * NV + i] = bnb[i * 256 + d] - mean * a;
}

// WRITE=0: stats, 1 slab/phase, X'[2]+raw[2] (79872 B -> 2 blocks/CU: the
// R11 change. R8-R10 lockstep at 1 block/CU had zero co-resident work to
// hide phase stalls; a second block provides it without touching the phase).
// WRITE=1: output pass, R9 structure verbatim (X'[2]+raw[3]+O, ~HBM floor).
// 8 waves x 64. Wave wv owns d-strip [wv*32,wv*32+32) and slab chunk
// [wv*CH,(wv+1)*CH) f32x4. x0 staged to LDS via async global_load_lds.
template <int WRITE>
__global__ __launch_bounds__(512) void k_gemm(
    const float* __restrict__ x0, const short* __restrict__ Wt,
    const unsigned* __restrict__ tab, float* __restrict__ sum, float* __restrict__ ssq,
    const float* __restrict__ An2, const float* __restrict__ Bn2,
    float* __restrict__ out) {
  __shared__ char smem[WRITE ? 126976 : 79872];
  constexpr int ROFF = WRITE ? ROFF1 : ROFF0;
  constexpr int NXB = 2;               // X' buffers
  constexpr int NRB = WRITE ? 3 : 2;   // raw buffers
  constexpr int NB  = WRITE ? NB1 : NB0;
  float* O = (float*)(smem + OOFF1);

  const int tid = threadIdx.x;
  const int lane = tid & 63;
  const int wv = tid >> 6;     // 0..7
  const int l15 = lane & 15;
  const int lg = lane >> 4;
  const int d0 = wv * 32;
  const int ch0 = wv * CH;
  const int fr0 = fsw(l15) << 4;        // read-side swizzle, rows l15 / 16+l15
  const int fr1 = fsw(16 + l15) << 4;

  // B fragments, register-resident: B[k=c][n=d] = Wt[d][c]
  s16x8 bfr[2][8];
#pragma unroll
  for (int nt = 0; nt < 2; ++nt)
#pragma unroll
    for (int kt = 0; kt < 8; ++kt)
      bfr[nt][kt] = *(const s16x8*)(Wt + (d0 + nt * 16 + l15) * 256 + kt * 32 + lg * 8);

  // formation table, register-resident (n-invariant)
  u32x4 tbr[NS];
#pragma unroll
  for (int s = 0; s < NS; ++s)
    if (s * 64 + lane < CH) tbr[s] = *(const u32x4*)(tab + 4 * (ch0 + s * 64 + lane));

  // BN affine tables, register-resident (n-invariant), WRITE only
  f32x4 anr[NS], bnr[NS];
  if (WRITE) {
#pragma unroll
    for (int s = 0; s < NS; ++s)
      if (s * 64 + lane < CH) {
        anr[s] = *(const f32x4*)(An2 + 4 * (ch0 + s * 64 + lane));
        bnr[s] = *(const f32x4*)(Bn2 + 4 * (ch0 + s * 64 + lane));
      }
  }

  // zero pad rows 23..31 of both X' buffers (never written again)
  for (int i = tid; i < NXB * 1152; i += 512) {
    int b = i / 1152;
    *(int*)(smem + b * 16384 + 11776 + (i - b * 1152) * 4) = 0;
  }

  float s1[2][2][4], s2[2][2][4];
  if (!WRITE) {
#pragma unroll
    for (int mt = 0; mt < 2; ++mt)
#pragma unroll
      for (int nt = 0; nt < 2; ++nt)
#pragma unroll
        for (int r = 0; r < 4; ++r) { s1[mt][nt][r] = 0.f; s2[mt][nt][r] = 0.f; }
  }

  const int nbase = blockIdx.x * NB;
  // pass 2 runs its window in reverse: pass 1 left the tail L3-resident
  auto nmap = [&](int T) { return nbase + (WRITE ? (NB - 1 - T) : T); };

  auto stage = [&](int T) {  // 23 exact DMAs for slab T -> raw[T%NRB]
    if (T >= NB) return;
    const char* gs = (const char*)(x0 + (size_t)nmap(T) * FLAT);
    char* lb = smem + ROFF + (T % NRB) * SLAB;
    gl_lds16(gs + (wv << 10) + lane * 16, lb + (wv << 10));
    gl_lds16(gs + ((8 + wv) << 10) + lane * 16, lb + ((8 + wv) << 10));
    if (wv < 7)
      gl_lds16(gs + ((16 + wv) << 10) + lane * 16, lb + ((16 + wv) << 10));
  };
  auto form = [&](int T) {  // X' formation into Xb[T%NXB] from raw[T%NRB]
    if (T >= NB) return;
    const char* rb = smem + ROFF + (T % NRB) * SLAB;
    char* xb = smem + (T % NXB) * 16384;
#pragma unroll
    for (int s = 0; s < NS; ++s)
      if (s * 64 + lane < CH) {
        f32x4 xv = *(const f32x4*)(rb + (ch0 + s * 64 + lane) * 16);
        u32x4 tb = tbr[s];
#pragma unroll
        for (int e = 0; e < 4; ++e) {
          unsigned tt = tb[e];
          *(short*)(xb + (tt & 0xffffu)) =
              (short)f2bf(xv[e] * __uint_as_float(tt & 0xffff0000u));
        }
      }
  };
  auto mstep = [&](int T, f32x4 (*acc)[2]) {  // y = X'(T) * W
    const char* xb = smem + (T % NXB) * 16384;
#pragma unroll
    for (int kt = 0; kt < 8; ++kt) {
      s16x8 af[2];
      af[0] = *(const s16x8*)(xb + (l15 << 9) + ((kt * 64 + lg * 16) ^ fr0));
      af[1] = *(const s16x8*)(xb + ((16 + l15) << 9) + ((kt * 64 + lg * 16) ^ fr1));
#pragma unroll
      for (int mt = 0; mt < 2; ++mt)
#pragma unroll
        for (int nt = 0; nt < 2; ++nt)
          acc[mt][nt] = __builtin_amdgcn_mfma_f32_16x16x32_bf16(
              af[mt], bfr[nt][kt], acc[mt][nt], 0, 0, 0);
    }
  };
  auto bar = []() {  // LDS-drain barrier: does NOT drain vmcnt
    asm volatile("s_waitcnt lgkmcnt(0)" ::: "memory");
    __builtin_amdgcn_s_barrier();
    asm volatile("" ::: "memory");
  };

  if (!WRITE) {
    // ---------------- stats pass: 1 slab/phase, 2-deep buffers ----------------
    stage(0); stage(1);
    asm volatile("s_waitcnt vmcnt(0)" ::: "memory");
    bar();
    form(0);
    for (int t = 0; t < NB0; ++t) {
      asm volatile("s_waitcnt vmcnt(0)" ::: "memory");  // DMA(t+1) landed
      bar();  // all waves' DMA(t+1) + form(t) visible; prev readers done
      stage(t + 2);  // -> raw[t&1], last read by form(t) in phase t-1
      f32x4 acc[2][2];
      __builtin_amdgcn_s_setprio(1);
#pragma unroll
      for (int mt = 0; mt < 2; ++mt)
#pragma unroll
        for (int nt = 0; nt < 2; ++nt) acc[mt][nt] = (f32x4){0.f, 0.f, 0.f, 0.f};
      mstep(t, acc);
      __builtin_amdgcn_s_setprio(0);
#pragma unroll
      for (int mt = 0; mt < 2; ++mt)
#pragma unroll
        for (int nt = 0; nt < 2; ++nt)
#pragma unroll
          for (int r = 0; r < 4; ++r) {
            float y = acc[mt][nt][r];
            s1[mt][nt][r] += y;
            s2[mt][nt][r] += y * y;
          }
      form(t + 1);  // raw[(t+1)&1] -> X'[(t+1)&1] (last read by mstep(t-1))
    }
#pragma unroll
    for (int mt = 0; mt < 2; ++mt)
#pragma unroll
      for (int nt = 0; nt < 2; ++nt)
#pragma unroll
        for (int r = 0; r < 4; ++r) {
          int w = mt * 16 + lg * 4 + r;
          if (w < NV) {
            int d = d0 + nt * 16 + l15;
            atomicAdd(sum + (w << 8) + d, s1[mt][nt][r]);
            atomicAdd(ssq + (w << 8) + d, s2[mt][nt][r]);
          }
        }
    return;
  }

  // ---------------- output pass: 1 slab per phase (R9 verbatim) ----------------
  stage(0); stage(1);
  asm volatile("s_waitcnt vmcnt(0)" ::: "memory");
  bar();
  form(0);

  for (int t = 0; t < NB1; ++t) {
    // own L(t+1) DMAs complete; allow epilogue(t-1) NT stores (3) to linger
    if (t) asm volatile("s_waitcnt vmcnt(3)" ::: "memory");
    else   asm volatile("s_waitcnt vmcnt(0)" ::: "memory");
    bar();  // all waves' L(t+1) + X'(t) form visible; raw/X' readers done
    stage(t + 2);
    form(t + 1);

    f32x4 acc[2][2];
#pragma unroll
    for (int mt = 0; mt < 2; ++mt)
#pragma unroll
      for (int nt = 0; nt < 2; ++nt) acc[mt][nt] = (f32x4){0.f, 0.f, 0.f, 0.f};
    __builtin_amdgcn_s_setprio(1);
    mstep(t, acc);
    __builtin_amdgcn_s_setprio(0);

    // scatter y -> O at out-shifted j = d*23 + (w+d)%23 (wave-local region)
#pragma unroll
    for (int mt = 0; mt < 2; ++mt)
#pragma unroll
      for (int nt = 0; nt < 2; ++nt)
#pragma unroll
        for (int r = 0; r < 4; ++r) {
          int w = mt * 16 + lg * 4 + r;  // C/D: row = (lane>>4)*4 + reg
          if (w < NV) {
            int d = d0 + nt * 16 + l15;  // col = lane & 15
            int sj = w + d; sj -= NV * divNV(sj);
            O[d * NV + sj] = acc[mt][nt][r];
          }
        }
    // same-wave readback: normalize + residual (raw LDS) + relu, NT store
    const char* rb = smem + ROFF + (t % NRB) * SLAB;
    float* og = out + (size_t)nmap(t) * FLAT;
#pragma unroll
    for (int s = 0; s < NS; ++s)
      if (s * 64 + lane < CH) {
        int i = ch0 + s * 64 + lane;
        f32x4 y = *(const f32x4*)(O + 4 * i);
        f32x4 sl = *(const f32x4*)(rb + i * 16);
        f32x4 o;
#pragma unroll
        for (int e = 0; e < 4; ++e)
          o[e] = fmaxf(fmaf(y[e], anr[s][e], bnr[s][e]) + sl[e], 0.0f);
        __builtin_nontemporal_store(o, (f32x4*)og + i);
      }
  }
}

extern "C" void kernel_launch(void* const* d_in, const int* in_sizes, int n_in,
                              void* d_out, int out_size, void* d_ws, size_t ws_size,
                              hipStream_t stream) {
  const float* x0   = (const float*)d_in[0];
  const float* W    = (const float*)d_in[1];
  // d_in[2] = bias: cancels inside BN -> unused
  const float* mask = (const float*)d_in[3];
  const float* bnw  = (const float*)d_in[4];
  const float* bnb  = (const float*)d_in[5];
  // d_in[6], d_in[7] = shift tables: folded into addressing
  float* out = (float*)d_out;

  char* ws = (char*)d_ws;
  short* Wt     = (short*)ws;
  unsigned* tab = (unsigned*)(ws + 131072);
  float* sum    = (float*)(ws + 154624);
  float* ssq    = (float*)(ws + 178176);
  float* An2    = (float*)(ws + 201728);
  float* Bn2    = (float*)(ws + 225280);

  k_prep<<<256, 256, 0, stream>>>(W, mask, Wt, tab, sum);
  k_gemm<0><<<1024, 512, 0, stream>>>(x0, Wt, tab, sum, ssq, nullptr, nullptr, nullptr);
  k_finalize<<<23, 256, 0, stream>>>(sum, ssq, bnw, bnb, An2, Bn2);
  k_gemm<1><<<512, 512, 0, stream>>>(x0, Wt, tab, sum, ssq, An2, Bn2, out);
}

// Round 12
// 276.759 us; speedup vs baseline: 1.1066x; 1.1066x over previous
//
#include <hip/hip_runtime.h>
#include <hip/hip_bf16.h>

#define NV 23
#define NTOT 16384
#define FLAT (NV * 256)    // 5888 floats per slab
#define FLAT4 (FLAT / 4)   // 1472
#define CH 184             // f32x4 per wave (1472/8)
#define NS 3               // reg slots per chunk (64+64+56)
#define SLAB 23552         // slab bytes

// stats: X'[4]@0 (65536) | raw[4]@65536 (94208) -> 159744, grid 256 x NB0=64
#define NB0 64
#define ROFF0 65536
// write: X'[2]@0 (32768) | raw[3]@32768 (70656) | O@103424 -> 126976, grid 512 x NB1=32
#define NB1 32
#define ROFF1 32768
#define OOFF1 103424

#define NPART 256          // stats grid == number of partial slots
#define PSUM_OFF 262144    // ws offsets for partial buffers
#define PSSQ_OFF (262144 + NPART * FLAT * 4)
#define WS_NEED (PSSQ_OFF + NPART * FLAT * 4)

typedef short s16x8 __attribute__((ext_vector_type(8)));
typedef float f32x4 __attribute__((ext_vector_type(4)));
typedef unsigned u32x4 __attribute__((ext_vector_type(4)));

// x/23 for 0 <= x < 61681
__device__ __forceinline__ int divNV(int x) { return (int)(((unsigned)x * 45591u) >> 20); }
// f32 -> bf16 bits, RNE
__device__ __forceinline__ unsigned f2bf(float f) {
  unsigned u = __float_as_uint(f);
  u += 0x7fffu + ((u >> 16) & 1u);
  return u >> 16;
}
// X' column swizzle (16-B granules): 6 distinct groups for w-strides of 4
// (form writes ~conflict-free), read rows pair-wise 2-way (free).
__device__ __forceinline__ int fsw(int w) { return ((w + (w >> 3)) * 3) & 7; }

// async global->LDS DMA, 16B per lane (lds dest wave-uniform, HW adds lane*16)
__device__ __forceinline__ void gl_lds16(const void* g, void* l) {
  __builtin_amdgcn_global_load_lds(
      (const __attribute__((address_space(1))) unsigned*)(unsigned long long)(uintptr_t)g,
      (__attribute__((address_space(3))) unsigned*)(unsigned)(uintptr_t)l, 16, 0, 0);
}

// ws layout (bytes): Wt@0 (131072) | tab@131072 (23552) | sum@154624 | ssq@178176
//                    | An2@201728 | Bn2@225280 | psum@262144 | pssq -> ~12.3MB
__global__ void k_prep(const float* __restrict__ W, const float* __restrict__ mask,
                       short* __restrict__ Wt, unsigned* __restrict__ tab,
                       float* __restrict__ sums) {
  int idx = blockIdx.x * 256 + threadIdx.x;  // grid 256 -> 65536
  int d = idx >> 8, c = idx & 255;
  Wt[idx] = (short)f2bf(W[c * 256 + d]);     // W^T in bf16: Wt[d][c]
  if (idx < FLAT) {
    // p = idx = c*23 + v ; w = (v - c) mod 23 ; swizzled LDS byte offset
    int cc = divNV(idx);
    int v = idx - NV * cc;
    int cm = cc - NV * divNV(cc);
    int w = v - cm; w += (w >> 31) & NV;
    unsigned off = (unsigned)((w << 9) + ((cc << 1) ^ (fsw(w) << 4)));
    tab[idx] = (f2bf(tanhf(mask[(w << 8) + cc]) + 1.0f) << 16) | off;
  }
  if (idx < 2 * FLAT) sums[idx] = 0.0f;      // zero sum+ssq (atomic fallback)
}

// grid 92 x 256. Partial path: reduce NPART per-block partials (layout
// [block][feature], coalesced reads) -> mean/var -> An2/Bn2. Fallback: sum/ssq.
__global__ void k_finalize(const float* __restrict__ sum, const float* __restrict__ ssq,
                           const float* __restrict__ psum, const float* __restrict__ pssq,
                           const float* __restrict__ bnw, const float* __restrict__ bnb,
                           float* __restrict__ An2, float* __restrict__ Bn2) {
  __shared__ float red[2][4][64];
  const int t = threadIdx.x;
  const int f0 = blockIdx.x * 64;
  if (psum) {
    const int fl = t & 63, c = t >> 6;   // 4 chunks x 64 partials each
    float S = 0.f, Q = 0.f;
    for (int b = 0; b < 64; ++b) {
      S += psum[(size_t)(c * 64 + b) * FLAT + f0 + fl];
      Q += pssq[(size_t)(c * 64 + b) * FLAT + f0 + fl];
    }
    red[0][c][fl] = S;
    red[1][c][fl] = Q;
    __syncthreads();
  }
  if (t < 64) {
    int idx = f0 + t;
    float S, Q;
    if (psum) {
      S = red[0][0][t] + red[0][1][t] + red[0][2][t] + red[0][3][t];
      Q = red[1][0][t] + red[1][1][t] + red[1][2][t] + red[1][3][t];
    } else {
      S = sum[idx]; Q = ssq[idx];
    }
    int w = idx >> 8, d = idx & 255;
    float mean = S * (1.0f / NTOT);
    float var  = Q * (1.0f / NTOT) - mean * mean;
    float inv  = rsqrtf(var + 1e-5f);
    int i = w + d; i -= NV * divNV(i);       // out-shift row i = (w+d) % 23
    float a = inv * bnw[i * 256 + d];
    An2[d * NV + i] = a;                     // j-indexed (flat out order)
    Bn2[d * NV + i] = bnb[i * 256 + d] - mean * a;
  }
}

// WRITE=0: stats (2 slabs/phase, X'[4]+raw[4]); block partials -> global
// stream stores (no atomic RMW tail; R11 evidence: atomic tail scales with
// grid and costs ~15-25us). WRITE=1: output pass (R9 structure verbatim).
template <int WRITE>
__global__ __launch_bounds__(512) void k_gemm(
    const float* __restrict__ x0, const short* __restrict__ Wt,
    const unsigned* __restrict__ tab, float* __restrict__ sum, float* __restrict__ ssq,
    float* __restrict__ psum, float* __restrict__ pssq,
    const float* __restrict__ An2, const float* __restrict__ Bn2,
    float* __restrict__ out) {
  __shared__ char smem[WRITE ? 126976 : 159744];
  constexpr int ROFF = WRITE ? ROFF1 : ROFF0;
  constexpr int NXB = WRITE ? 2 : 4;   // X' buffers
  constexpr int NRB = WRITE ? 3 : 4;   // raw buffers
  constexpr int NB  = WRITE ? NB1 : NB0;
  float* O = (float*)(smem + OOFF1);

  const int tid = threadIdx.x;
  const int lane = tid & 63;
  const int wv = tid >> 6;     // 0..7
  const int l15 = lane & 15;
  const int lg = lane >> 4;
  const int d0 = wv * 32;
  const int ch0 = wv * CH;
  const int fr0 = fsw(l15) << 4;        // read-side swizzle, rows l15 / 16+l15
  const int fr1 = fsw(16 + l15) << 4;

  // B fragments, register-resident: B[k=c][n=d] = Wt[d][c]
  s16x8 bfr[2][8];
#pragma unroll
  for (int nt = 0; nt < 2; ++nt)
#pragma unroll
    for (int kt = 0; kt < 8; ++kt)
      bfr[nt][kt] = *(const s16x8*)(Wt + (d0 + nt * 16 + l15) * 256 + kt * 32 + lg * 8);

  // formation table, register-resident (n-invariant)
  u32x4 tbr[NS];
#pragma unroll
  for (int s = 0; s < NS; ++s)
    if (s * 64 + lane < CH) tbr[s] = *(const u32x4*)(tab + 4 * (ch0 + s * 64 + lane));

  // BN affine tables, register-resident (n-invariant), WRITE only
  f32x4 anr[NS], bnr[NS];
  if (WRITE) {
#pragma unroll
    for (int s = 0; s < NS; ++s)
      if (s * 64 + lane < CH) {
        anr[s] = *(const f32x4*)(An2 + 4 * (ch0 + s * 64 + lane));
        bnr[s] = *(const f32x4*)(Bn2 + 4 * (ch0 + s * 64 + lane));
      }
  }

  // zero pad rows 23..31 of all X' buffers (never written again)
  for (int i = tid; i < NXB * 1152; i += 512) {
    int b = i / 1152;
    *(int*)(smem + b * 16384 + 11776 + (i - b * 1152) * 4) = 0;
  }

  float s1[2][2][4], s2[2][2][4];
  if (!WRITE) {
#pragma unroll
    for (int mt = 0; mt < 2; ++mt)
#pragma unroll
      for (int nt = 0; nt < 2; ++nt)
#pragma unroll
        for (int r = 0; r < 4; ++r) { s1[mt][nt][r] = 0.f; s2[mt][nt][r] = 0.f; }
  }

  const int nbase = blockIdx.x * NB;
  // pass 2 runs its window in reverse: pass 1 left the tail L3-resident
  auto nmap = [&](int T) { return nbase + (WRITE ? (NB - 1 - T) : T); };

  auto stage = [&](int T) {  // 23 exact DMAs for slab T -> raw[T%NRB]
    if (T >= NB) return;
    const char* gs = (const char*)(x0 + (size_t)nmap(T) * FLAT);
    char* lb = smem + ROFF + (T % NRB) * SLAB;
    gl_lds16(gs + (wv << 10) + lane * 16, lb + (wv << 10));
    gl_lds16(gs + ((8 + wv) << 10) + lane * 16, lb + ((8 + wv) << 10));
    if (wv < 7)
      gl_lds16(gs + ((16 + wv) << 10) + lane * 16, lb + ((16 + wv) << 10));
  };
  auto form = [&](int T) {  // X' formation into Xb[T%NXB] from raw[T%NRB]
    if (T >= NB) return;
    const char* rb = smem + ROFF + (T % NRB) * SLAB;
    char* xb = smem + (T % NXB) * 16384;
#pragma unroll
    for (int s = 0; s < NS; ++s)
      if (s * 64 + lane < CH) {
        f32x4 xv = *(const f32x4*)(rb + (ch0 + s * 64 + lane) * 16);
        u32x4 tb = tbr[s];
#pragma unroll
        for (int e = 0; e < 4; ++e) {
          unsigned tt = tb[e];
          *(short*)(xb + (tt & 0xffffu)) =
              (short)f2bf(xv[e] * __uint_as_float(tt & 0xffff0000u));
        }
      }
  };
  auto mstep = [&](int T, f32x4 (*acc)[2]) {  // y = X'(T) * W
    const char* xb = smem + (T % NXB) * 16384;
#pragma unroll
    for (int kt = 0; kt < 8; ++kt) {
      s16x8 af[2];
      af[0] = *(const s16x8*)(xb + (l15 << 9) + ((kt * 64 + lg * 16) ^ fr0));
      af[1] = *(const s16x8*)(xb + ((16 + l15) << 9) + ((kt * 64 + lg * 16) ^ fr1));
#pragma unroll
      for (int mt = 0; mt < 2; ++mt)
#pragma unroll
        for (int nt = 0; nt < 2; ++nt)
          acc[mt][nt] = __builtin_amdgcn_mfma_f32_16x16x32_bf16(
              af[mt], bfr[nt][kt], acc[mt][nt], 0, 0, 0);
    }
  };
  auto sstep = [&](f32x4 (*acc)[2]) {
#pragma unroll
    for (int mt = 0; mt < 2; ++mt)
#pragma unroll
      for (int nt = 0; nt < 2; ++nt)
#pragma unroll
        for (int r = 0; r < 4; ++r) {
          float y = acc[mt][nt][r];
          s1[mt][nt][r] += y;
          s2[mt][nt][r] += y * y;
        }
  };
  auto bar = []() {  // LDS-drain barrier: does NOT drain vmcnt
    asm volatile("s_waitcnt lgkmcnt(0)" ::: "memory");
    __builtin_amdgcn_s_barrier();
    asm volatile("" ::: "memory");
  };

  if (!WRITE) {
    // ---------------- stats pass: 2 slabs per phase ----------------
    stage(0); stage(1); stage(2); stage(3);
    asm volatile("s_waitcnt vmcnt(0)" ::: "memory");
    bar();
    form(0); form(1);
    for (int u = 0; u < NB0 / 2; ++u) {
      int t = 2 * u;
      asm volatile("s_waitcnt vmcnt(0)" ::: "memory");  // prev phase's stages done
      bar();  // all waves' DMAs + forms visible; prev readers done
      stage(t + 4); stage(t + 5);
      form(t + 2); form(t + 3);
      f32x4 acc[2][2];
      __builtin_amdgcn_s_setprio(1);
#pragma unroll
      for (int mt = 0; mt < 2; ++mt)
#pragma unroll
        for (int nt = 0; nt < 2; ++nt) acc[mt][nt] = (f32x4){0.f, 0.f, 0.f, 0.f};
      mstep(t, acc);
      sstep(acc);
#pragma unroll
      for (int mt = 0; mt < 2; ++mt)
#pragma unroll
        for (int nt = 0; nt < 2; ++nt) acc[mt][nt] = (f32x4){0.f, 0.f, 0.f, 0.f};
      mstep(t + 1, acc);
      __builtin_amdgcn_s_setprio(0);
      sstep(acc);
    }
    if (psum) {
      // stream partials: [block][feature], plain stores, no RMW
      float* ps = psum + (size_t)blockIdx.x * FLAT;
      float* pq = pssq + (size_t)blockIdx.x * FLAT;
#pragma unroll
      for (int mt = 0; mt < 2; ++mt)
#pragma unroll
        for (int nt = 0; nt < 2; ++nt)
#pragma unroll
          for (int r = 0; r < 4; ++r) {
            int w = mt * 16 + lg * 4 + r;
            if (w < NV) {
              int d = d0 + nt * 16 + l15;
              __builtin_nontemporal_store(s1[mt][nt][r], ps + (w << 8) + d);
              __builtin_nontemporal_store(s2[mt][nt][r], pq + (w << 8) + d);
            }
          }
    } else {
#pragma unroll
      for (int mt = 0; mt < 2; ++mt)
#pragma unroll
        for (int nt = 0; nt < 2; ++nt)
#pragma unroll
          for (int r = 0; r < 4; ++r) {
            int w = mt * 16 + lg * 4 + r;
            if (w < NV) {
              int d = d0 + nt * 16 + l15;
              atomicAdd(sum + (w << 8) + d, s1[mt][nt][r]);
              atomicAdd(ssq + (w << 8) + d, s2[mt][nt][r]);
            }
          }
    }
    return;
  }

  // ---------------- output pass: 1 slab per phase (R9 verbatim) ----------------
  stage(0); stage(1);
  asm volatile("s_waitcnt vmcnt(0)" ::: "memory");
  bar();
  form(0);

  for (int t = 0; t < NB1; ++t) {
    // own L(t+1) DMAs complete; allow epilogue(t-1) NT stores (3) to linger
    if (t) asm volatile("s_waitcnt vmcnt(3)" ::: "memory");
    else   asm volatile("s_waitcnt vmcnt(0)" ::: "memory");
    bar();  // all waves' L(t+1) + X'(t) form visible; raw/X' readers done
    stage(t + 2);
    form(t + 1);

    f32x4 acc[2][2];
#pragma unroll
    for (int mt = 0; mt < 2; ++mt)
#pragma unroll
      for (int nt = 0; nt < 2; ++nt) acc[mt][nt] = (f32x4){0.f, 0.f, 0.f, 0.f};
    __builtin_amdgcn_s_setprio(1);
    mstep(t, acc);
    __builtin_amdgcn_s_setprio(0);

    // scatter y -> O at out-shifted j = d*23 + (w+d)%23 (wave-local region)
#pragma unroll
    for (int mt = 0; mt < 2; ++mt)
#pragma unroll
      for (int nt = 0; nt < 2; ++nt)
#pragma unroll
        for (int r = 0; r < 4; ++r) {
          int w = mt * 16 + lg * 4 + r;  // C/D: row = (lane>>4)*4 + reg
          if (w < NV) {
            int d = d0 + nt * 16 + l15;  // col = lane & 15
            int sj = w + d; sj -= NV * divNV(sj);
            O[d * NV + sj] = acc[mt][nt][r];
          }
        }
    // same-wave readback: normalize + residual (raw LDS) + relu, NT store
    const char* rb = smem + ROFF + (t % NRB) * SLAB;
    float* og = out + (size_t)nmap(t) * FLAT;
#pragma unroll
    for (int s = 0; s < NS; ++s)
      if (s * 64 + lane < CH) {
        int i = ch0 + s * 64 + lane;
        f32x4 y = *(const f32x4*)(O + 4 * i);
        f32x4 sl = *(const f32x4*)(rb + i * 16);
        f32x4 o;
#pragma unroll
        for (int e = 0; e < 4; ++e)
          o[e] = fmaxf(fmaf(y[e], anr[s][e], bnr[s][e]) + sl[e], 0.0f);
        __builtin_nontemporal_store(o, (f32x4*)og + i);
      }
  }
}

extern "C" void kernel_launch(void* const* d_in, const int* in_sizes, int n_in,
                              void* d_out, int out_size, void* d_ws, size_t ws_size,
                              hipStream_t stream) {
  const float* x0   = (const float*)d_in[0];
  const float* W    = (const float*)d_in[1];
  // d_in[2] = bias: cancels inside BN -> unused
  const float* mask = (const float*)d_in[3];
  const float* bnw  = (const float*)d_in[4];
  const float* bnb  = (const float*)d_in[5];
  // d_in[6], d_in[7] = shift tables: folded into addressing
  float* out = (float*)d_out;

  char* ws = (char*)d_ws;
  short* Wt     = (short*)ws;
  unsigned* tab = (unsigned*)(ws + 131072);
  float* sum    = (float*)(ws + 154624);
  float* ssq    = (float*)(ws + 178176);
  float* An2    = (float*)(ws + 201728);
  float* Bn2    = (float*)(ws + 225280);
  bool part = ws_size >= (size_t)WS_NEED;
  float* psum = part ? (float*)(ws + PSUM_OFF) : nullptr;
  float* pssq = part ? (float*)(ws + PSSQ_OFF) : nullptr;

  k_prep<<<256, 256, 0, stream>>>(W, mask, Wt, tab, sum);
  k_gemm<0><<<256, 512, 0, stream>>>(x0, Wt, tab, sum, ssq, psum, pssq, nullptr, nullptr, nullptr);
  k_finalize<<<92, 256, 0, stream>>>(sum, ssq, psum, pssq, bnw, bnb, An2, Bn2);
  k_gemm<1><<<512, 512, 0, stream>>>(x0, Wt, tab, sum, ssq, nullptr, nullptr, An2, Bn2, out);
}

// Round 13
// 262.115 us; speedup vs baseline: 1.1684x; 1.0559x over previous
//
#include <hip/hip_runtime.h>
#include <hip/hip_bf16.h>

#define NV 23
#define NTOT 16384
#define FLAT (NV * 256)    // 5888 floats per slab
#define FLAT4 (FLAT / 4)   // 1472
#define CH 184             // f32x4 per wave (1472/8)
#define NS 3               // reg slots per chunk (64+64+56)
#define SLAB 23552         // slab bytes

// stats: X8'[4]@0 (32768, fp8 32x256B each) | raw[4]@32768 (94208) -> 126976
#define NB0 64
#define ROFF0 32768
// write: X'[2]@0 (32768) | raw[3]@32768 (70656) | O@103424 -> 126976, grid 512 x NB1=32
#define NB1 32
#define ROFF1 32768
#define OOFF1 103424

#define NPART 256
#define WT8_OFF 248832
#define TAB8_OFF 314368
#define PSUM_OFF 337920
#define PSSQ_OFF (PSUM_OFF + NPART * FLAT * 4)
#define WS_NEED (PSSQ_OFF + NPART * FLAT * 4)

typedef short s16x8 __attribute__((ext_vector_type(8)));
typedef float f32x4 __attribute__((ext_vector_type(4)));
typedef unsigned u32x4 __attribute__((ext_vector_type(4)));
typedef long long i64t;

// x/23 for 0 <= x < 61681
__device__ __forceinline__ int divNV(int x) { return (int)(((unsigned)x * 45591u) >> 20); }
// f32 -> bf16 bits, RNE
__device__ __forceinline__ unsigned f2bf(float f) {
  unsigned u = __float_as_uint(f);
  u += 0x7fffu + ((u >> 16) & 1u);
  return u >> 16;
}
// X' column swizzle (16-B granules): 6 distinct groups for w-strides of 4
// (form writes ~conflict-free), reads uniform across bank cycle.
__device__ __forceinline__ int fsw(int w) { return ((w + (w >> 3)) * 3) & 7; }

// async global->LDS DMA, 16B per lane (lds dest wave-uniform, HW adds lane*16)
__device__ __forceinline__ void gl_lds16(const void* g, void* l) {
  __builtin_amdgcn_global_load_lds(
      (const __attribute__((address_space(1))) unsigned*)(unsigned long long)(uintptr_t)g,
      (__attribute__((address_space(3))) unsigned*)(unsigned)(uintptr_t)l, 16, 0, 0);
}

// ws: Wt@0 | tab@131072 | sum@154624 | ssq@178176 | An2@201728 | Bn2@225280
//     | Wt8@248832 (65536, e4m3) | tab8@314368 (23552) | psum | pssq -> ~12.4MB
__global__ void k_prep(const float* __restrict__ W, const float* __restrict__ mask,
                       short* __restrict__ Wt, char* __restrict__ Wt8,
                       unsigned* __restrict__ tab, unsigned* __restrict__ tab8,
                       float* __restrict__ sums) {
  int idx = blockIdx.x * 256 + threadIdx.x;  // grid 256 -> 65536
  int d = idx >> 8, c = idx & 255;
  float wv = W[c * 256 + d];
  Wt[idx] = (short)f2bf(wv);                 // W^T bf16: Wt[d][c]
  Wt8[idx] = (char)__builtin_amdgcn_cvt_pk_fp8_f32(wv, wv, 0, false);  // e4m3
  if (idx < FLAT) {
    // p = idx = c*23 + v ; w = (v - c) mod 23
    int cc = divNV(idx);
    int v = idx - NV * cc;
    int cm = cc - NV * divNV(cc);
    int w = v - cm; w += (w >> 31) & NV;
    unsigned m2b = f2bf(tanhf(mask[(w << 8) + cc]) + 1.0f) << 16;
    tab[idx]  = m2b | (unsigned)((w << 9) + ((cc << 1) ^ (fsw(w) << 4)));  // bf16 X'
    tab8[idx] = m2b | (unsigned)((w << 8) + (cc ^ (fsw(w) << 4)));          // fp8 X'
  }
  if (idx < 2 * FLAT) sums[idx] = 0.0f;      // zero sum+ssq (atomic fallback)
}

// grid 92 x 256. Partial path: reduce NPART per-block partials; else sum/ssq.
__global__ void k_finalize(const float* __restrict__ sum, const float* __restrict__ ssq,
                           const float* __restrict__ psum, const float* __restrict__ pssq,
                           const float* __restrict__ bnw, const float* __restrict__ bnb,
                           float* __restrict__ An2, float* __restrict__ Bn2) {
  __shared__ float red[2][4][64];
  const int t = threadIdx.x;
  const int f0 = blockIdx.x * 64;
  if (psum) {
    const int fl = t & 63, c = t >> 6;
    float S = 0.f, Q = 0.f;
    for (int b = 0; b < 64; ++b) {
      S += psum[(size_t)(c * 64 + b) * FLAT + f0 + fl];
      Q += pssq[(size_t)(c * 64 + b) * FLAT + f0 + fl];
    }
    red[0][c][fl] = S;
    red[1][c][fl] = Q;
    __syncthreads();
  }
  if (t < 64) {
    int idx = f0 + t;
    float S, Q;
    if (psum) {
      S = red[0][0][t] + red[0][1][t] + red[0][2][t] + red[0][3][t];
      Q = red[1][0][t] + red[1][1][t] + red[1][2][t] + red[1][3][t];
    } else {
      S = sum[idx]; Q = ssq[idx];
    }
    int w = idx >> 8, d = idx & 255;
    float mean = S * (1.0f / NTOT);
    float var  = Q * (1.0f / NTOT) - mean * mean;
    float inv  = rsqrtf(var + 1e-5f);
    int i = w + d; i -= NV * divNV(i);       // out-shift row i = (w+d) % 23
    float a = inv * bnw[i * 256 + d];
    An2[d * NV + i] = a;
    Bn2[d * NV + i] = bnb[i * 256 + d] - mean * a;
  }
}

// Stats pass in FP8 (e4m3): X' tile halves to 8KB/wave -> mstep LDS-port
// work ~halves (R12 post-mortem: stats is LDS-port bound at ~2700cy/slab/CU,
// A-reads dominant). Quantization error is statistical only (BN stats),
// ~0.2% var error. Structure = R12 stats (2 slabs/phase, 4-deep buffers).
__global__ __launch_bounds__(512) void k_stats(
    const float* __restrict__ x0, const char* __restrict__ Wt8,
    const unsigned* __restrict__ tab8, float* __restrict__ sum, float* __restrict__ ssq,
    float* __restrict__ psum, float* __restrict__ pssq) {
  __shared__ char smem[126976];  // X8'[4] | raw[4]

  const int tid = threadIdx.x;
  const int lane = tid & 63;
  const int wv = tid >> 6;
  const int l15 = lane & 15;
  const int lg = lane >> 4;
  const int d0 = wv * 32;
  const int ch0 = wv * CH;
  const int fr0 = fsw(l15) << 4;
  const int fr1 = fsw(16 + l15) << 4;

  // B fragments fp8 (32 VGPR): B[k=c][n=d] = Wt8[d][c], 8B per kt
  i64t bfr8[2][8];
#pragma unroll
  for (int nt = 0; nt < 2; ++nt)
#pragma unroll
    for (int kt = 0; kt < 8; ++kt)
      bfr8[nt][kt] = *(const i64t*)(Wt8 + (d0 + nt * 16 + l15) * 256 + kt * 32 + lg * 8);

  u32x4 tbr[NS];
#pragma unroll
  for (int s = 0; s < NS; ++s)
    if (s * 64 + lane < CH) tbr[s] = *(const u32x4*)(tab8 + 4 * (ch0 + s * 64 + lane));

  // zero pad rows 23..31 of the 4 X8' buffers (2304B each)
  for (int i = tid; i < 2304; i += 512) {
    int b = i / 576;
    *(int*)(smem + b * 8192 + 5888 + (i - b * 576) * 4) = 0;
  }

  float s1[2][2][4], s2[2][2][4];
#pragma unroll
  for (int mt = 0; mt < 2; ++mt)
#pragma unroll
    for (int nt = 0; nt < 2; ++nt)
#pragma unroll
      for (int r = 0; r < 4; ++r) { s1[mt][nt][r] = 0.f; s2[mt][nt][r] = 0.f; }

  const int nbase = blockIdx.x * NB0;

  auto stage = [&](int T) {  // 23 exact DMAs for slab T -> raw[T%4]
    if (T >= NB0) return;
    const char* gs = (const char*)(x0 + (size_t)(nbase + T) * FLAT);
    char* lb = smem + ROFF0 + (T % 4) * SLAB;
    gl_lds16(gs + (wv << 10) + lane * 16, lb + (wv << 10));
    gl_lds16(gs + ((8 + wv) << 10) + lane * 16, lb + ((8 + wv) << 10));
    if (wv < 7)
      gl_lds16(gs + ((16 + wv) << 10) + lane * 16, lb + ((16 + wv) << 10));
  };
  auto form = [&](int T) {  // fp8 X' into X8[T%4] from raw[T%4]
    if (T >= NB0) return;
    const char* rb = smem + ROFF0 + (T % 4) * SLAB;
    char* xb = smem + (T % 4) * 8192;
#pragma unroll
    for (int s = 0; s < NS; ++s)
      if (s * 64 + lane < CH) {
        f32x4 xv = *(const f32x4*)(rb + (ch0 + s * 64 + lane) * 16);
        u32x4 tb = tbr[s];
        float v0 = xv[0] * __uint_as_float(tb[0] & 0xffff0000u);
        float v1 = xv[1] * __uint_as_float(tb[1] & 0xffff0000u);
        float v2 = xv[2] * __uint_as_float(tb[2] & 0xffff0000u);
        float v3 = xv[3] * __uint_as_float(tb[3] & 0xffff0000u);
        int u01 = __builtin_amdgcn_cvt_pk_fp8_f32(v0, v1, 0, false);
        int u23 = __builtin_amdgcn_cvt_pk_fp8_f32(v2, v3, 0, false);
        xb[tb[0] & 0xffffu] = (char)u01;
        xb[tb[1] & 0xffffu] = (char)(u01 >> 8);
        xb[tb[2] & 0xffffu] = (char)u23;
        xb[tb[3] & 0xffffu] = (char)(u23 >> 8);
      }
  };
  auto mstep = [&](int T, f32x4 (*acc)[2]) {  // y = X8'(T) * W8
    const char* xb = smem + (T % 4) * 8192;
#pragma unroll
    for (int kt = 0; kt < 8; ++kt) {
      i64t a0 = *(const i64t*)(xb + (l15 << 8) + ((kt * 32 + lg * 8) ^ fr0));
      i64t a1 = *(const i64t*)(xb + ((16 + l15) << 8) + ((kt * 32 + lg * 8) ^ fr1));
#pragma unroll
      for (int nt = 0; nt < 2; ++nt) {
        acc[0][nt] = __builtin_amdgcn_mfma_f32_16x16x32_fp8_fp8(a0, bfr8[nt][kt], acc[0][nt], 0, 0, 0);
        acc[1][nt] = __builtin_amdgcn_mfma_f32_16x16x32_fp8_fp8(a1, bfr8[nt][kt], acc[1][nt], 0, 0, 0);
      }
    }
  };
  auto sstep = [&](f32x4 (*acc)[2]) {
#pragma unroll
    for (int mt = 0; mt < 2; ++mt)
#pragma unroll
      for (int nt = 0; nt < 2; ++nt)
#pragma unroll
        for (int r = 0; r < 4; ++r) {
          float y = acc[mt][nt][r];
          s1[mt][nt][r] += y;
          s2[mt][nt][r] += y * y;
        }
  };
  auto bar = []() {
    asm volatile("s_waitcnt lgkmcnt(0)" ::: "memory");
    __builtin_amdgcn_s_barrier();
    asm volatile("" ::: "memory");
  };

  stage(0); stage(1); stage(2); stage(3);
  asm volatile("s_waitcnt vmcnt(0)" ::: "memory");
  bar();
  form(0); form(1);
  for (int u = 0; u < NB0 / 2; ++u) {
    int t = 2 * u;
    asm volatile("s_waitcnt vmcnt(0)" ::: "memory");
    bar();
    stage(t + 4); stage(t + 5);
    form(t + 2); form(t + 3);
    f32x4 acc[2][2];
    __builtin_amdgcn_s_setprio(1);
#pragma unroll
    for (int mt = 0; mt < 2; ++mt)
#pragma unroll
      for (int nt = 0; nt < 2; ++nt) acc[mt][nt] = (f32x4){0.f, 0.f, 0.f, 0.f};
    mstep(t, acc);
    sstep(acc);
#pragma unroll
    for (int mt = 0; mt < 2; ++mt)
#pragma unroll
      for (int nt = 0; nt < 2; ++nt) acc[mt][nt] = (f32x4){0.f, 0.f, 0.f, 0.f};
    mstep(t + 1, acc);
    __builtin_amdgcn_s_setprio(0);
    sstep(acc);
  }
  if (psum) {
    float* ps = psum + (size_t)blockIdx.x * FLAT;
    float* pq = pssq + (size_t)blockIdx.x * FLAT;
#pragma unroll
    for (int mt = 0; mt < 2; ++mt)
#pragma unroll
      for (int nt = 0; nt < 2; ++nt)
#pragma unroll
        for (int r = 0; r < 4; ++r) {
          int w = mt * 16 + lg * 4 + r;
          if (w < NV) {
            int d = d0 + nt * 16 + l15;
            __builtin_nontemporal_store(s1[mt][nt][r], ps + (w << 8) + d);
            __builtin_nontemporal_store(s2[mt][nt][r], pq + (w << 8) + d);
          }
        }
  } else {
#pragma unroll
    for (int mt = 0; mt < 2; ++mt)
#pragma unroll
      for (int nt = 0; nt < 2; ++nt)
#pragma unroll
        for (int r = 0; r < 4; ++r) {
          int w = mt * 16 + lg * 4 + r;
          if (w < NV) {
            int d = d0 + nt * 16 + l15;
            atomicAdd(sum + (w << 8) + d, s1[mt][nt][r]);
            atomicAdd(ssq + (w << 8) + d, s2[mt][nt][r]);
          }
        }
  }
}

// Output pass: bf16 (accuracy), R12/R9 structure verbatim.
__global__ __launch_bounds__(512) void k_write(
    const float* __restrict__ x0, const short* __restrict__ Wt,
    const unsigned* __restrict__ tab,
    const float* __restrict__ An2, const float* __restrict__ Bn2,
    float* __restrict__ out) {
  __shared__ char smem[126976];  // X'[2] | raw[3] | O
  float* O = (float*)(smem + OOFF1);

  const int tid = threadIdx.x;
  const int lane = tid & 63;
  const int wv = tid >> 6;
  const int l15 = lane & 15;
  const int lg = lane >> 4;
  const int d0 = wv * 32;
  const int ch0 = wv * CH;
  const int fr0 = fsw(l15) << 4;
  const int fr1 = fsw(16 + l15) << 4;

  s16x8 bfr[2][8];
#pragma unroll
  for (int nt = 0; nt < 2; ++nt)
#pragma unroll
    for (int kt = 0; kt < 8; ++kt)
      bfr[nt][kt] = *(const s16x8*)(Wt + (d0 + nt * 16 + l15) * 256 + kt * 32 + lg * 8);

  u32x4 tbr[NS];
#pragma unroll
  for (int s = 0; s < NS; ++s)
    if (s * 64 + lane < CH) tbr[s] = *(const u32x4*)(tab + 4 * (ch0 + s * 64 + lane));

  f32x4 anr[NS], bnr[NS];
#pragma unroll
  for (int s = 0; s < NS; ++s)
    if (s * 64 + lane < CH) {
      anr[s] = *(const f32x4*)(An2 + 4 * (ch0 + s * 64 + lane));
      bnr[s] = *(const f32x4*)(Bn2 + 4 * (ch0 + s * 64 + lane));
    }

  for (int i = tid; i < 2304; i += 512) {
    int b = i >= 1152;
    *(int*)(smem + b * 16384 + 11776 + (i - b * 1152) * 4) = 0;
  }

  const int nbase = blockIdx.x * NB1;
  auto nmap = [&](int T) { return nbase + (NB1 - 1 - T); };  // reverse: L3 tail

  auto stage = [&](int T) {
    if (T >= NB1) return;
    const char* gs = (const char*)(x0 + (size_t)nmap(T) * FLAT);
    char* lb = smem + ROFF1 + (T % 3) * SLAB;
    gl_lds16(gs + (wv << 10) + lane * 16, lb + (wv << 10));
    gl_lds16(gs + ((8 + wv) << 10) + lane * 16, lb + ((8 + wv) << 10));
    if (wv < 7)
      gl_lds16(gs + ((16 + wv) << 10) + lane * 16, lb + ((16 + wv) << 10));
  };
  auto form = [&](int T) {
    if (T >= NB1) return;
    const char* rb = smem + ROFF1 + (T % 3) * SLAB;
    char* xb = smem + (T & 1) * 16384;
#pragma unroll
    for (int s = 0; s < NS; ++s)
      if (s * 64 + lane < CH) {
        f32x4 xv = *(const f32x4*)(rb + (ch0 + s * 64 + lane) * 16);
        u32x4 tb = tbr[s];
#pragma unroll
        for (int e = 0; e < 4; ++e) {
          unsigned tt = tb[e];
          *(short*)(xb + (tt & 0xffffu)) =
              (short)f2bf(xv[e] * __uint_as_float(tt & 0xffff0000u));
        }
      }
  };
  auto bar = []() {
    asm volatile("s_waitcnt lgkmcnt(0)" ::: "memory");
    __builtin_amdgcn_s_barrier();
    asm volatile("" ::: "memory");
  };

  stage(0); stage(1);
  asm volatile("s_waitcnt vmcnt(0)" ::: "memory");
  bar();
  form(0);

  for (int t = 0; t < NB1; ++t) {
    if (t) asm volatile("s_waitcnt vmcnt(3)" ::: "memory");
    else   asm volatile("s_waitcnt vmcnt(0)" ::: "memory");
    bar();
    stage(t + 2);
    form(t + 1);

    const char* xb = smem + (t & 1) * 16384;
    f32x4 acc[2][2];
#pragma unroll
    for (int mt = 0; mt < 2; ++mt)
#pragma unroll
      for (int nt = 0; nt < 2; ++nt) acc[mt][nt] = (f32x4){0.f, 0.f, 0.f, 0.f};
    __builtin_amdgcn_s_setprio(1);
#pragma unroll
    for (int kt = 0; kt < 8; ++kt) {
      s16x8 af[2];
      af[0] = *(const s16x8*)(xb + (l15 << 9) + ((kt * 64 + lg * 16) ^ fr0));
      af[1] = *(const s16x8*)(xb + ((16 + l15) << 9) + ((kt * 64 + lg * 16) ^ fr1));
#pragma unroll
      for (int mt = 0; mt < 2; ++mt)
#pragma unroll
        for (int nt = 0; nt < 2; ++nt)
          acc[mt][nt] = __builtin_amdgcn_mfma_f32_16x16x32_bf16(
              af[mt], bfr[nt][kt], acc[mt][nt], 0, 0, 0);
    }
    __builtin_amdgcn_s_setprio(0);

#pragma unroll
    for (int mt = 0; mt < 2; ++mt)
#pragma unroll
      for (int nt = 0; nt < 2; ++nt)
#pragma unroll
        for (int r = 0; r < 4; ++r) {
          int w = mt * 16 + lg * 4 + r;
          if (w < NV) {
            int d = d0 + nt * 16 + l15;
            int sj = w + d; sj -= NV * divNV(sj);
            O[d * NV + sj] = acc[mt][nt][r];
          }
        }
    const char* rb = smem + ROFF1 + (t % 3) * SLAB;
    float* og = out + (size_t)nmap(t) * FLAT;
#pragma unroll
    for (int s = 0; s < NS; ++s)
      if (s * 64 + lane < CH) {
        int i = ch0 + s * 64 + lane;
        f32x4 y = *(const f32x4*)(O + 4 * i);
        f32x4 sl = *(const f32x4*)(rb + i * 16);
        f32x4 o;
#pragma unroll
        for (int e = 0; e < 4; ++e)
          o[e] = fmaxf(fmaf(y[e], anr[s][e], bnr[s][e]) + sl[e], 0.0f);
        __builtin_nontemporal_store(o, (f32x4*)og + i);
      }
  }
}

extern "C" void kernel_launch(void* const* d_in, const int* in_sizes, int n_in,
                              void* d_out, int out_size, void* d_ws, size_t ws_size,
                              hipStream_t stream) {
  const float* x0   = (const float*)d_in[0];
  const float* W    = (const float*)d_in[1];
  // d_in[2] = bias: cancels inside BN -> unused
  const float* mask = (const float*)d_in[3];
  const float* bnw  = (const float*)d_in[4];
  const float* bnb  = (const float*)d_in[5];
  // d_in[6], d_in[7] = shift tables: folded into addressing
  float* out = (float*)d_out;

  char* ws = (char*)d_ws;
  short* Wt      = (short*)ws;
  unsigned* tab  = (unsigned*)(ws + 131072);
  float* sum     = (float*)(ws + 154624);
  float* ssq     = (float*)(ws + 178176);
  float* An2     = (float*)(ws + 201728);
  float* Bn2     = (float*)(ws + 225280);
  char* Wt8      = ws + WT8_OFF;
  unsigned* tab8 = (unsigned*)(ws + TAB8_OFF);
  bool part = ws_size >= (size_t)WS_NEED;
  float* psum = part ? (float*)(ws + PSUM_OFF) : nullptr;
  float* pssq = part ? (float*)(ws + PSSQ_OFF) : nullptr;

  k_prep<<<256, 256, 0, stream>>>(W, mask, Wt, Wt8, tab, tab8, sum);
  k_stats<<<256, 512, 0, stream>>>(x0, Wt8, tab8, sum, ssq, psum, pssq);
  k_finalize<<<92, 256, 0, stream>>>(sum, ssq, psum, pssq, bnw, bnb, An2, Bn2);
  k_write<<<512, 512, 0, stream>>>(x0, Wt, tab, An2, Bn2, out);
}

// Round 14
// 249.544 us; speedup vs baseline: 1.2273x; 1.0504x over previous
//
#include <hip/hip_runtime.h>
#include <hip/hip_bf16.h>

#define NV 23
#define NTOT 16384
#define FLAT (NV * 256)    // 5888 floats per slab
#define FLAT4 (FLAT / 4)   // 1472
#define CH 184             // f32x4 per wave (1472/8)
#define NS 3               // reg slots per chunk (64+64+56)
#define SLAB 23552         // slab bytes

// stats: X8'[4]@0 (32768, fp8 32x256B each) | raw[4]@32768 (94208) -> 126976
#define NB0 64
#define ROFF0 32768
// write: X'[2]@0 (32768) | raw[3]@32768 (70656) | O@103424 -> 126976, grid 256 x NB1=64
#define NB1 64
#define ROFF1 32768
#define OOFF1 103424

#define NPART 256
#define WT8_OFF 248832
#define TAB8_OFF 314368
#define PSUM_OFF 337920
#define PSSQ_OFF (PSUM_OFF + NPART * FLAT * 4)
#define WS_NEED (PSSQ_OFF + NPART * FLAT * 4)

typedef short s16x8 __attribute__((ext_vector_type(8)));
typedef float f32x4 __attribute__((ext_vector_type(4)));
typedef unsigned u32x4 __attribute__((ext_vector_type(4)));
typedef long long i64t;

// x/23 for 0 <= x < 61681
__device__ __forceinline__ int divNV(int x) { return (int)(((unsigned)x * 45591u) >> 20); }
// f32 -> bf16 bits, RNE
__device__ __forceinline__ unsigned f2bf(float f) {
  unsigned u = __float_as_uint(f);
  u += 0x7fffu + ((u >> 16) & 1u);
  return u >> 16;
}
// X' column swizzle (16-B granules): 6 distinct groups for w-strides of 4
// (form writes ~conflict-free), reads uniform across bank cycle.
__device__ __forceinline__ int fsw(int w) { return ((w + (w >> 3)) * 3) & 7; }

// async global->LDS DMA, 16B per lane (lds dest wave-uniform, HW adds lane*16)
__device__ __forceinline__ void gl_lds16(const void* g, void* l) {
  __builtin_amdgcn_global_load_lds(
      (const __attribute__((address_space(1))) unsigned*)(unsigned long long)(uintptr_t)g,
      (__attribute__((address_space(3))) unsigned*)(unsigned)(uintptr_t)l, 16, 0, 0);
}

// ws: Wt@0 | tab@131072 | sum@154624 | ssq@178176 | An2@201728 | Bn2@225280
//     | Wt8@248832 (65536, e4m3) | tab8@314368 (23552) | psum | pssq -> ~12.4MB
__global__ void k_prep(const float* __restrict__ W, const float* __restrict__ mask,
                       short* __restrict__ Wt, char* __restrict__ Wt8,
                       unsigned* __restrict__ tab, unsigned* __restrict__ tab8,
                       float* __restrict__ sums) {
  int idx = blockIdx.x * 256 + threadIdx.x;  // grid 256 -> 65536
  int d = idx >> 8, c = idx & 255;
  float wv = W[c * 256 + d];
  Wt[idx] = (short)f2bf(wv);                 // W^T bf16: Wt[d][c]
  Wt8[idx] = (char)__builtin_amdgcn_cvt_pk_fp8_f32(wv, wv, 0, false);  // e4m3
  if (idx < FLAT) {
    // p = idx = c*23 + v ; w = (v - c) mod 23
    int cc = divNV(idx);
    int v = idx - NV * cc;
    int cm = cc - NV * divNV(cc);
    int w = v - cm; w += (w >> 31) & NV;
    unsigned m2b = f2bf(tanhf(mask[(w << 8) + cc]) + 1.0f) << 16;
    tab[idx]  = m2b | (unsigned)((w << 9) + ((cc << 1) ^ (fsw(w) << 4)));  // bf16 X'
    tab8[idx] = m2b | (unsigned)((w << 8) + (cc ^ (fsw(w) << 4)));          // fp8 X'
  }
  if (idx < 2 * FLAT) sums[idx] = 0.0f;      // zero sum+ssq (atomic fallback)
}

// grid 92 x 256. Partial path: reduce NPART per-block partials; else sum/ssq.
__global__ void k_finalize(const float* __restrict__ sum, const float* __restrict__ ssq,
                           const float* __restrict__ psum, const float* __restrict__ pssq,
                           const float* __restrict__ bnw, const float* __restrict__ bnb,
                           float* __restrict__ An2, float* __restrict__ Bn2) {
  __shared__ float red[2][4][64];
  const int t = threadIdx.x;
  const int f0 = blockIdx.x * 64;
  if (psum) {
    const int fl = t & 63, c = t >> 6;
    float S = 0.f, Q = 0.f;
    for (int b = 0; b < 64; ++b) {
      S += psum[(size_t)(c * 64 + b) * FLAT + f0 + fl];
      Q += pssq[(size_t)(c * 64 + b) * FLAT + f0 + fl];
    }
    red[0][c][fl] = S;
    red[1][c][fl] = Q;
    __syncthreads();
  }
  if (t < 64) {
    int idx = f0 + t;
    float S, Q;
    if (psum) {
      S = red[0][0][t] + red[0][1][t] + red[0][2][t] + red[0][3][t];
      Q = red[1][0][t] + red[1][1][t] + red[1][2][t] + red[1][3][t];
    } else {
      S = sum[idx]; Q = ssq[idx];
    }
    int w = idx >> 8, d = idx & 255;
    float mean = S * (1.0f / NTOT);
    float var  = Q * (1.0f / NTOT) - mean * mean;
    float inv  = rsqrtf(var + 1e-5f);
    int i = w + d; i -= NV * divNV(i);       // out-shift row i = (w+d) % 23
    float a = inv * bnw[i * 256 + d];
    An2[d * NV + i] = a;
    Bn2[d * NV + i] = bnb[i * 256 + d] - mean * a;
  }
}

// Stats pass FP8 (e4m3). R14: mstep preloads ALL 16 A-fragments (32 regs)
// before the 32-MFMA burst -> the per-kt read->lgkm-wait->MFMA chain becomes
// 16 overlapped reads + small in-order waits (lgkm-chain isolation test).
__global__ __launch_bounds__(512) void k_stats(
    const float* __restrict__ x0, const char* __restrict__ Wt8,
    const unsigned* __restrict__ tab8, float* __restrict__ sum, float* __restrict__ ssq,
    float* __restrict__ psum, float* __restrict__ pssq) {
  __shared__ char smem[126976];  // X8'[4] | raw[4]

  const int tid = threadIdx.x;
  const int lane = tid & 63;
  const int wv = tid >> 6;
  const int l15 = lane & 15;
  const int lg = lane >> 4;
  const int d0 = wv * 32;
  const int ch0 = wv * CH;
  const int fr0 = fsw(l15) << 4;
  const int fr1 = fsw(16 + l15) << 4;

  // B fragments fp8 (32 VGPR): B[k=c][n=d] = Wt8[d][c], 8B per kt
  i64t bfr8[2][8];
#pragma unroll
  for (int nt = 0; nt < 2; ++nt)
#pragma unroll
    for (int kt = 0; kt < 8; ++kt)
      bfr8[nt][kt] = *(const i64t*)(Wt8 + (d0 + nt * 16 + l15) * 256 + kt * 32 + lg * 8);

  u32x4 tbr[NS];
#pragma unroll
  for (int s = 0; s < NS; ++s)
    if (s * 64 + lane < CH) tbr[s] = *(const u32x4*)(tab8 + 4 * (ch0 + s * 64 + lane));

  // zero pad rows 23..31 of the 4 X8' buffers (2304B each)
  for (int i = tid; i < 2304; i += 512) {
    int b = i / 576;
    *(int*)(smem + b * 8192 + 5888 + (i - b * 576) * 4) = 0;
  }

  float s1[2][2][4], s2[2][2][4];
#pragma unroll
  for (int mt = 0; mt < 2; ++mt)
#pragma unroll
    for (int nt = 0; nt < 2; ++nt)
#pragma unroll
      for (int r = 0; r < 4; ++r) { s1[mt][nt][r] = 0.f; s2[mt][nt][r] = 0.f; }

  const int nbase = blockIdx.x * NB0;

  auto stage = [&](int T) {  // 23 exact DMAs for slab T -> raw[T%4]
    if (T >= NB0) return;
    const char* gs = (const char*)(x0 + (size_t)(nbase + T) * FLAT);
    char* lb = smem + ROFF0 + (T % 4) * SLAB;
    gl_lds16(gs + (wv << 10) + lane * 16, lb + (wv << 10));
    gl_lds16(gs + ((8 + wv) << 10) + lane * 16, lb + ((8 + wv) << 10));
    if (wv < 7)
      gl_lds16(gs + ((16 + wv) << 10) + lane * 16, lb + ((16 + wv) << 10));
  };
  auto form = [&](int T) {  // fp8 X' into X8[T%4] from raw[T%4]
    if (T >= NB0) return;
    const char* rb = smem + ROFF0 + (T % 4) * SLAB;
    char* xb = smem + (T % 4) * 8192;
#pragma unroll
    for (int s = 0; s < NS; ++s)
      if (s * 64 + lane < CH) {
        f32x4 xv = *(const f32x4*)(rb + (ch0 + s * 64 + lane) * 16);
        u32x4 tb = tbr[s];
        float v0 = xv[0] * __uint_as_float(tb[0] & 0xffff0000u);
        float v1 = xv[1] * __uint_as_float(tb[1] & 0xffff0000u);
        float v2 = xv[2] * __uint_as_float(tb[2] & 0xffff0000u);
        float v3 = xv[3] * __uint_as_float(tb[3] & 0xffff0000u);
        int u01 = __builtin_amdgcn_cvt_pk_fp8_f32(v0, v1, 0, false);
        int u23 = __builtin_amdgcn_cvt_pk_fp8_f32(v2, v3, 0, false);
        xb[tb[0] & 0xffffu] = (char)u01;
        xb[tb[1] & 0xffffu] = (char)(u01 >> 8);
        xb[tb[2] & 0xffffu] = (char)u23;
        xb[tb[3] & 0xffffu] = (char)(u23 >> 8);
      }
  };
  auto mstep = [&](int T, f32x4 (*acc)[2]) {  // y = X8'(T) * W8, A preloaded
    const char* xb = smem + (T % 4) * 8192;
    i64t a0[8], a1[8];
#pragma unroll
    for (int kt = 0; kt < 8; ++kt) {
      a0[kt] = *(const i64t*)(xb + (l15 << 8) + ((kt * 32 + lg * 8) ^ fr0));
      a1[kt] = *(const i64t*)(xb + ((16 + l15) << 8) + ((kt * 32 + lg * 8) ^ fr1));
    }
#pragma unroll
    for (int kt = 0; kt < 8; ++kt) {
#pragma unroll
      for (int nt = 0; nt < 2; ++nt) {
        acc[0][nt] = __builtin_amdgcn_mfma_f32_16x16x32_fp8_fp8(a0[kt], bfr8[nt][kt], acc[0][nt], 0, 0, 0);
        acc[1][nt] = __builtin_amdgcn_mfma_f32_16x16x32_fp8_fp8(a1[kt], bfr8[nt][kt], acc[1][nt], 0, 0, 0);
      }
    }
  };
  auto sstep = [&](f32x4 (*acc)[2]) {
#pragma unroll
    for (int mt = 0; mt < 2; ++mt)
#pragma unroll
      for (int nt = 0; nt < 2; ++nt)
#pragma unroll
        for (int r = 0; r < 4; ++r) {
          float y = acc[mt][nt][r];
          s1[mt][nt][r] += y;
          s2[mt][nt][r] += y * y;
        }
  };
  auto bar = []() {
    asm volatile("s_waitcnt lgkmcnt(0)" ::: "memory");
    __builtin_amdgcn_s_barrier();
    asm volatile("" ::: "memory");
  };

  stage(0); stage(1); stage(2); stage(3);
  asm volatile("s_waitcnt vmcnt(0)" ::: "memory");
  bar();
  form(0); form(1);
  for (int u = 0; u < NB0 / 2; ++u) {
    int t = 2 * u;
    asm volatile("s_waitcnt vmcnt(0)" ::: "memory");
    bar();
    stage(t + 4); stage(t + 5);
    form(t + 2); form(t + 3);
    f32x4 acc[2][2];
    __builtin_amdgcn_s_setprio(1);
#pragma unroll
    for (int mt = 0; mt < 2; ++mt)
#pragma unroll
      for (int nt = 0; nt < 2; ++nt) acc[mt][nt] = (f32x4){0.f, 0.f, 0.f, 0.f};
    mstep(t, acc);
    sstep(acc);
#pragma unroll
    for (int mt = 0; mt < 2; ++mt)
#pragma unroll
      for (int nt = 0; nt < 2; ++nt) acc[mt][nt] = (f32x4){0.f, 0.f, 0.f, 0.f};
    mstep(t + 1, acc);
    __builtin_amdgcn_s_setprio(0);
    sstep(acc);
  }
  if (psum) {
    float* ps = psum + (size_t)blockIdx.x * FLAT;
    float* pq = pssq + (size_t)blockIdx.x * FLAT;
#pragma unroll
    for (int mt = 0; mt < 2; ++mt)
#pragma unroll
      for (int nt = 0; nt < 2; ++nt)
#pragma unroll
        for (int r = 0; r < 4; ++r) {
          int w = mt * 16 + lg * 4 + r;
          if (w < NV) {
            int d = d0 + nt * 16 + l15;
            __builtin_nontemporal_store(s1[mt][nt][r], ps + (w << 8) + d);
            __builtin_nontemporal_store(s2[mt][nt][r], pq + (w << 8) + d);
          }
        }
  } else {
#pragma unroll
    for (int mt = 0; mt < 2; ++mt)
#pragma unroll
      for (int nt = 0; nt < 2; ++nt)
#pragma unroll
        for (int r = 0; r < 4; ++r) {
          int w = mt * 16 + lg * 4 + r;
          if (w < NV) {
            int d = d0 + nt * 16 + l15;
            atomicAdd(sum + (w << 8) + d, s1[mt][nt][r]);
            atomicAdd(ssq + (w << 8) + d, s2[mt][nt][r]);
          }
        }
  }
}

// Output pass: bf16 (accuracy), R9 structure; grid 256 x NB1=64 (one
// block-round instead of two: halves prologue/drain bubbles).
__global__ __launch_bounds__(512) void k_write(
    const float* __restrict__ x0, const short* __restrict__ Wt,
    const unsigned* __restrict__ tab,
    const float* __restrict__ An2, const float* __restrict__ Bn2,
    float* __restrict__ out) {
  __shared__ char smem[126976];  // X'[2] | raw[3] | O
  float* O = (float*)(smem + OOFF1);

  const int tid = threadIdx.x;
  const int lane = tid & 63;
  const int wv = tid >> 6;
  const int l15 = lane & 15;
  const int lg = lane >> 4;
  const int d0 = wv * 32;
  const int ch0 = wv * CH;
  const int fr0 = fsw(l15) << 4;
  const int fr1 = fsw(16 + l15) << 4;

  s16x8 bfr[2][8];
#pragma unroll
  for (int nt = 0; nt < 2; ++nt)
#pragma unroll
    for (int kt = 0; kt < 8; ++kt)
      bfr[nt][kt] = *(const s16x8*)(Wt + (d0 + nt * 16 + l15) * 256 + kt * 32 + lg * 8);

  u32x4 tbr[NS];
#pragma unroll
  for (int s = 0; s < NS; ++s)
    if (s * 64 + lane < CH) tbr[s] = *(const u32x4*)(tab + 4 * (ch0 + s * 64 + lane));

  f32x4 anr[NS], bnr[NS];
#pragma unroll
  for (int s = 0; s < NS; ++s)
    if (s * 64 + lane < CH) {
      anr[s] = *(const f32x4*)(An2 + 4 * (ch0 + s * 64 + lane));
      bnr[s] = *(const f32x4*)(Bn2 + 4 * (ch0 + s * 64 + lane));
    }

  for (int i = tid; i < 2304; i += 512) {
    int b = i >= 1152;
    *(int*)(smem + b * 16384 + 11776 + (i - b * 1152) * 4) = 0;
  }

  const int nbase = blockIdx.x * NB1;
  auto nmap = [&](int T) { return nbase + (NB1 - 1 - T); };  // reverse: L3 tail

  auto stage = [&](int T) {
    if (T >= NB1) return;
    const char* gs = (const char*)(x0 + (size_t)nmap(T) * FLAT);
    char* lb = smem + ROFF1 + (T % 3) * SLAB;
    gl_lds16(gs + (wv << 10) + lane * 16, lb + (wv << 10));
    gl_lds16(gs + ((8 + wv) << 10) + lane * 16, lb + ((8 + wv) << 10));
    if (wv < 7)
      gl_lds16(gs + ((16 + wv) << 10) + lane * 16, lb + ((16 + wv) << 10));
  };
  auto form = [&](int T) {
    if (T >= NB1) return;
    const char* rb = smem + ROFF1 + (T % 3) * SLAB;
    char* xb = smem + (T & 1) * 16384;
#pragma unroll
    for (int s = 0; s < NS; ++s)
      if (s * 64 + lane < CH) {
        f32x4 xv = *(const f32x4*)(rb + (ch0 + s * 64 + lane) * 16);
        u32x4 tb = tbr[s];
#pragma unroll
        for (int e = 0; e < 4; ++e) {
          unsigned tt = tb[e];
          *(short*)(xb + (tt & 0xffffu)) =
              (short)f2bf(xv[e] * __uint_as_float(tt & 0xffff0000u));
        }
      }
  };
  auto bar = []() {
    asm volatile("s_waitcnt lgkmcnt(0)" ::: "memory");
    __builtin_amdgcn_s_barrier();
    asm volatile("" ::: "memory");
  };

  stage(0); stage(1);
  asm volatile("s_waitcnt vmcnt(0)" ::: "memory");
  bar();
  form(0);

  for (int t = 0; t < NB1; ++t) {
    if (t) asm volatile("s_waitcnt vmcnt(3)" ::: "memory");
    else   asm volatile("s_waitcnt vmcnt(0)" ::: "memory");
    bar();
    stage(t + 2);
    form(t + 1);

    const char* xb = smem + (t & 1) * 16384;
    f32x4 acc[2][2];
#pragma unroll
    for (int mt = 0; mt < 2; ++mt)
#pragma unroll
      for (int nt = 0; nt < 2; ++nt) acc[mt][nt] = (f32x4){0.f, 0.f, 0.f, 0.f};
    __builtin_amdgcn_s_setprio(1);
#pragma unroll
    for (int kt = 0; kt < 8; ++kt) {
      s16x8 af[2];
      af[0] = *(const s16x8*)(xb + (l15 << 9) + ((kt * 64 + lg * 16) ^ fr0));
      af[1] = *(const s16x8*)(xb + ((16 + l15) << 9) + ((kt * 64 + lg * 16) ^ fr1));
#pragma unroll
      for (int mt = 0; mt < 2; ++mt)
#pragma unroll
        for (int nt = 0; nt < 2; ++nt)
          acc[mt][nt] = __builtin_amdgcn_mfma_f32_16x16x32_bf16(
              af[mt], bfr[nt][kt], acc[mt][nt], 0, 0, 0);
    }
    __builtin_amdgcn_s_setprio(0);

#pragma unroll
    for (int mt = 0; mt < 2; ++mt)
#pragma unroll
      for (int nt = 0; nt < 2; ++nt)
#pragma unroll
        for (int r = 0; r < 4; ++r) {
          int w = mt * 16 + lg * 4 + r;
          if (w < NV) {
            int d = d0 + nt * 16 + l15;
            int sj = w + d; sj -= NV * divNV(sj);
            O[d * NV + sj] = acc[mt][nt][r];
          }
        }
    const char* rb = smem + ROFF1 + (t % 3) * SLAB;
    float* og = out + (size_t)nmap(t) * FLAT;
#pragma unroll
    for (int s = 0; s < NS; ++s)
      if (s * 64 + lane < CH) {
        int i = ch0 + s * 64 + lane;
        f32x4 y = *(const f32x4*)(O + 4 * i);
        f32x4 sl = *(const f32x4*)(rb + i * 16);
        f32x4 o;
#pragma unroll
        for (int e = 0; e < 4; ++e)
          o[e] = fmaxf(fmaf(y[e], anr[s][e], bnr[s][e]) + sl[e], 0.0f);
        __builtin_nontemporal_store(o, (f32x4*)og + i);
      }
  }
}

extern "C" void kernel_launch(void* const* d_in, const int* in_sizes, int n_in,
                              void* d_out, int out_size, void* d_ws, size_t ws_size,
                              hipStream_t stream) {
  const float* x0   = (const float*)d_in[0];
  const float* W    = (const float*)d_in[1];
  // d_in[2] = bias: cancels inside BN -> unused
  const float* mask = (const float*)d_in[3];
  const float* bnw  = (const float*)d_in[4];
  const float* bnb  = (const float*)d_in[5];
  // d_in[6], d_in[7] = shift tables: folded into addressing
  float* out = (float*)d_out;

  char* ws = (char*)d_ws;
  short* Wt      = (short*)ws;
  unsigned* tab  = (unsigned*)(ws + 131072);
  float* sum     = (float*)(ws + 154624);
  float* ssq     = (float*)(ws + 178176);
  float* An2     = (float*)(ws + 201728);
  float* Bn2     = (float*)(ws + 225280);
  char* Wt8      = ws + WT8_OFF;
  unsigned* tab8 = (unsigned*)(ws + TAB8_OFF);
  bool part = ws_size >= (size_t)WS_NEED;
  float* psum = part ? (float*)(ws + PSUM_OFF) : nullptr;
  float* pssq = part ? (float*)(ws + PSSQ_OFF) : nullptr;

  k_prep<<<256, 256, 0, stream>>>(W, mask, Wt, Wt8, tab, tab8, sum);
  k_stats<<<256, 512, 0, stream>>>(x0, Wt8, tab8, sum, ssq, psum, pssq);
  k_finalize<<<92, 256, 0, stream>>>(sum, ssq, psum, pssq, bnw, bnb, An2, Bn2);
  k_write<<<256, 512, 0, stream>>>(x0, Wt, tab, An2, Bn2, out);
}